// Round 11
// baseline (182.061 us; speedup 1.0000x reference)
//
#include <hip/hip_runtime.h>
#include <hip/hip_bf16.h>
#include <math.h>

#define NV 131072
#define KOFF 27
#define ZROWS 64   // zero-pad region rows (spread hot line)
#define SENT (-32768)

typedef __attribute__((ext_vector_type(4))) float floatx4;
typedef __attribute__((ext_vector_type(4))) float float4v;
typedef __attribute__((ext_vector_type(2))) unsigned long ulong2v;
typedef __attribute__((ext_vector_type(4))) unsigned int uint4v;

__device__ inline float silu_f(float x) { return x / (1.0f + expf(-x)); }
__device__ inline unsigned int fp8_byte(float x) {
    return __builtin_amdgcn_cvt_pk_fp8_f32(x, x, 0, false) & 0xFF;
}

// h fp8 row layout (64 B): byte quad*16 + half*8 + j  <->  channel half*32 + quad*8 + j
// One 16-B load at quad*16 gives (av.x = ks0 fragment, av.y = ks1 fragment).

// ---------- fused pre kernel: role-partitioned grid ----------
// [0,512): nbr -> nbr_s [27][NV] int16 row-deltas (SENT = missing)
// [512,8704): LN1+silu -> h0 fp8 (16 lanes/row)
// [8704,8812): W1/W2 -> fp8 [k][cout][cin]
// [8812,8940): FiLM
// [8940]: zero-pad regions of h0/h2
__global__ void pre_kernel(const float* __restrict__ feats, const float* __restrict__ emb,
                           const float* __restrict__ gamma, const float* __restrict__ beta,
                           const float* __restrict__ W1, const float* __restrict__ W2,
                           const float* __restrict__ emb_W, const float* __restrict__ emb_b,
                           const int* __restrict__ nbr,
                           unsigned char* __restrict__ W1f, unsigned char* __restrict__ W2f,
                           float* __restrict__ ss, unsigned char* __restrict__ h0,
                           unsigned char* __restrict__ h2, short* __restrict__ nbr_s) {
    int gid = blockIdx.x, tid = threadIdx.x;
    if (gid < 512) {
        __shared__ int s[256 * KOFF];
        int r0 = gid * 256;
        for (int i = tid; i < 256 * KOFF; i += 256) s[i] = nbr[r0 * KOFF + i];
        __syncthreads();
        int r = r0 + tid;
#pragma unroll
        for (int k = 0; k < KOFF; ++k) {
            int v = s[tid * KOFF + k];
            nbr_s[k * NV + r] = (short)((v == NV) ? SENT : (v - r));  // |delta| <= 4161
        }
    } else if (gid < 8704) {
        int row = (gid - 512) * 16 + (tid >> 4);
        int t = tid & 15;
        float4v x = ((const float4v*)feats)[row * 16 + t];
        float s = x.x + x.y + x.z + x.w;
#pragma unroll
        for (int m = 1; m < 16; m <<= 1) s += __shfl_xor(s, m);
        float mu = s * (1.0f / 64.0f);
        float d0 = x.x - mu, d1 = x.y - mu, d2 = x.z - mu, d3 = x.w - mu;
        float q = d0 * d0 + d1 * d1 + d2 * d2 + d3 * d3;
#pragma unroll
        for (int m = 1; m < 16; m <<= 1) q += __shfl_xor(q, m);
        float inv = rsqrtf(q * (1.0f / 64.0f) + 1e-6f);
        float4v g = ((const float4v*)gamma)[t], b = ((const float4v*)beta)[t];
        float v0 = silu_f(d0 * inv * g.x + b.x);
        float v1 = silu_f(d1 * inv * g.y + b.y);
        float v2 = silu_f(d2 * inv * g.z + b.z);
        float v3 = silu_f(d3 * inv * g.w + b.w);
        unsigned int pk = __builtin_amdgcn_cvt_pk_fp8_f32(v0, v1, 0, false);
        pk = __builtin_amdgcn_cvt_pk_fp8_f32(v2, v3, pk, true);
        int pos = ((t >> 1) & 3) * 16 + (t >> 3) * 8 + (t & 1) * 4;
        *(unsigned int*)(h0 + row * 64 + pos) = pk;
    } else if (gid < 8812) {
        int t = (gid - 8704) * 256 + tid;  // dword idx < 27648
        if (t < 27648) {
            int k = t >> 10, rem = t & 1023, cout = rem >> 4, ci4 = (rem & 15) * 4;
            const float* wsrc1 = W1 + k * 4096 + ci4 * 64 + cout;
            const float* wsrc2 = W2 + k * 4096 + ci4 * 64 + cout;
            unsigned int p1 = __builtin_amdgcn_cvt_pk_fp8_f32(wsrc1[0], wsrc1[64], 0, false);
            p1 = __builtin_amdgcn_cvt_pk_fp8_f32(wsrc1[128], wsrc1[192], p1, true);
            unsigned int p2 = __builtin_amdgcn_cvt_pk_fp8_f32(wsrc2[0], wsrc2[64], 0, false);
            p2 = __builtin_amdgcn_cvt_pk_fp8_f32(wsrc2[128], wsrc2[192], p2, true);
            ((unsigned int*)W1f)[t] = p1;
            ((unsigned int*)W2f)[t] = p2;
        }
    } else if (gid < 8940) {
        int wv = (gid - 8812) * 4 + (tid >> 6);  // 0..511
        int lane = tid & 63;
        int b = wv >> 7, c = wv & 127;
        float acc = 0.0f;
#pragma unroll
        for (int i = 0; i < 8; ++i) {
            int e = i * 64 + lane;
            acc += silu_f(emb[b * 512 + e]) * emb_W[e * 128 + c];
        }
#pragma unroll
        for (int m = 1; m < 64; m <<= 1) acc += __shfl_xor(acc, m);
        if (lane == 0) ss[wv] = acc + emb_b[c];
    } else {
        if (tid < 256) {
            uint4v z = (uint4v){0, 0, 0, 0};
            ((uint4v*)(h0 + NV * 64))[tid] = z;
            ((uint4v*)(h2 + NV * 64))[tid] = z;
        }
    }
}

// ---------- gather-MFMA sparse conv, fp8, 2-k-per-phase staging ----------
// 32 rows/wave, 128 rows/block, 1024 blocks = 4 blocks/CU (16 waves: TLP across barriers).
// W staged 2 k-offsets per dbuf phase -> only 14 barriers/kernel.
template <int EPI>
__global__ __launch_bounds__(256, 4) void conv_kernel(
    const unsigned char* __restrict__ hsrc,    // [NV+ZROWS, 64B] fp8 permuted rows
    const unsigned char* __restrict__ Wf,      // [27][64][64] fp8 (k, cout, cin)
    const short* __restrict__ nbr_s,           // [27, NV] int16 deltas
    const int* __restrict__ batch_idx,         // [NV]
    const float* __restrict__ ss,              // [4, 128]
    const float* __restrict__ bias,            // [64]
    const float* __restrict__ feats,           // [NV, 64] (EPI=1)
    unsigned char* __restrict__ dst_f8, float* __restrict__ dst_f32) {
    __shared__ char sW[4 * 4608];  // 4 tiles (2 phases x 2 k), 64 rows x 72 B each
    __shared__ float s_ss[512];

    int tid = threadIdx.x, lane = tid & 63, wave = tid >> 6;
    int l15 = lane & 15, quad = lane >> 4;
    int lb = (blockIdx.x & 7) * 128 + (blockIdx.x >> 3);  // XCD-contiguous logical block
    int roww = lb * 128 + wave * 32;

    if (EPI == 0) {
        s_ss[tid] = ss[tid];
        s_ss[tid + 256] = ss[tid + 256];
    }

    const char* hb = (const char*)hsrc;
    const ulong2v* w16 = (const ulong2v*)Wf;  // 16B chunks: k*256 + c
    char* sbase = (char*)sW;

    // staging: chunk c (=tid) -> LDS row c>>2 (stride 72), slot c&3
    int pw = (tid >> 2) * 72 + (tid & 3) * 16;
    // B read addr within a tile: cout*72 + quad*8 (+ n*1152, + ks*32)
    int vb = l15 * 72 + quad * 8;

    const short* nps = nbr_s + roww + l15;
    unsigned int qoff = (unsigned int)(quad * 16);
    // per-m gather bases (include qoff); wave-uniform zero-row offset (includes qoff)
    unsigned int bo[2];
#pragma unroll
    for (int m = 0; m < 2; ++m) bo[m] = (unsigned int)((roww + m * 16 + l15) << 6) + qoff;
    unsigned int zoq = (unsigned int)((NV + (lb & (ZROWS - 1))) << 6) + qoff;

    // prologue: idx(0) -> A(0); idx(1) -> regs; stage pair0 (k0,k1); pair1 -> regs
    short dn[2];
    ulong2v ac[2];
#pragma unroll
    for (int m = 0; m < 2; ++m) {
        short d0 = nps[m * 16];
        unsigned int o = (d0 == SENT) ? zoq : (bo[m] + (unsigned int)((int)d0 << 6));
        ac[m] = *(const ulong2v*)(hb + o);
        dn[m] = nps[NV + m * 16];
    }
    *(ulong2v*)(sbase + pw) = w16[tid];
    *(ulong2v*)(sbase + 4608 + pw) = w16[256 + tid];
    ulong2v Br0 = w16[2 * 256 + tid], Br1 = w16[3 * 256 + tid];

    floatx4 acc[2][4];
#pragma unroll
    for (int m = 0; m < 2; ++m)
#pragma unroll
        for (int n = 0; n < 4; ++n) acc[m][n] = (floatx4){0.f, 0.f, 0.f, 0.f};

    __asm__ __volatile__("s_waitcnt lgkmcnt(0)" ::: "memory");
    __builtin_amdgcn_s_barrier();

#define CITER(K, KB)                                                                          \
    {                                                                                         \
        int kp2 = ((K) + 2 < KOFF) ? (K) + 2 : KOFF - 1;                                      \
        short d2[2];                                                                          \
        _Pragma("unroll") for (int m = 0; m < 2; ++m) d2[m] = nps[(size_t)kp2 * NV + m * 16]; \
        ulong2v an[2];                                                                        \
        _Pragma("unroll") for (int m = 0; m < 2; ++m) {                                       \
            int dd = (int)dn[m];                                                              \
            unsigned int o = (dd == SENT) ? zoq : (bo[m] + (unsigned int)(dd << 6));          \
            an[m] = *(const ulong2v*)(hb + o);                                                \
        }                                                                                     \
        const char* kb = sbase + (KB);                                                        \
        long bf0[4], bf1[4];                                                                  \
        _Pragma("unroll") for (int n = 0; n < 4; ++n)                                         \
            bf0[n] = *(const long*)(kb + vb + n * 1152);                                      \
        _Pragma("unroll") for (int n = 0; n < 4; ++n)                                         \
            bf1[n] = *(const long*)(kb + vb + n * 1152 + 32);                                 \
        _Pragma("unroll") for (int m = 0; m < 2; ++m) {                                       \
            long a0 = (long)ac[m].x;                                                          \
            _Pragma("unroll") for (int n = 0; n < 4; ++n)                                     \
                acc[m][n] = __builtin_amdgcn_mfma_f32_16x16x32_fp8_fp8(a0, bf0[n], acc[m][n], 0, 0, 0); \
        }                                                                                     \
        _Pragma("unroll") for (int m = 0; m < 2; ++m) {                                       \
            long a1 = (long)ac[m].y;                                                          \
            _Pragma("unroll") for (int n = 0; n < 4; ++n)                                     \
                acc[m][n] = __builtin_amdgcn_mfma_f32_16x16x32_fp8_fp8(a1, bf1[n], acc[m][n], 0, 0, 0); \
        }                                                                                     \
        _Pragma("unroll") for (int m = 0; m < 2; ++m) { ac[m] = an[m]; dn[m] = d2[m]; }       \
    }

    // phases 0..12: k = 2p, 2p+1 from cur buf; stage pair p+1 -> oth; prefetch pair p+2
#pragma unroll 1
    for (int p = 0; p < 13; ++p) {
        int cur = (p & 1) ? 9216 : 0;
        int oth = (p & 1) ? 0 : 9216;
        *(ulong2v*)(sbase + oth + pw) = Br0;
        *(ulong2v*)(sbase + oth + 4608 + pw) = Br1;
        int ks0 = (2 * p + 4 < KOFF) ? 2 * p + 4 : KOFF - 1;
        int ks1 = (2 * p + 5 < KOFF) ? 2 * p + 5 : KOFF - 1;
        ulong2v Bn0 = w16[ks0 * 256 + tid];
        ulong2v Bn1 = w16[ks1 * 256 + tid];
        CITER(2 * p, cur);
        CITER(2 * p + 1, cur + 4608);
        __asm__ __volatile__("s_waitcnt lgkmcnt(0)" ::: "memory");
        __builtin_amdgcn_s_barrier();
        Br0 = Bn0;
        Br1 = Bn1;
    }
    // phase 13: k = 26 from cur buf (13&1 -> 9216)
    CITER(26, 9216);
#undef CITER

    // epilogue: C/D layout col = lane&15, row = quad*4 + r
    float bias_v[4];
#pragma unroll
    for (int n = 0; n < 4; ++n) bias_v[n] = bias[n * 16 + l15];

#pragma unroll
    for (int m = 0; m < 2; ++m) {
#pragma unroll
        for (int r = 0; r < 4; ++r) {
            int row = roww + m * 16 + quad * 4 + r;
            float v[4];
#pragma unroll
            for (int n = 0; n < 4; ++n) v[n] = acc[m][n][r] + bias_v[n];
            if (EPI == 0) {
                float s = v[0] + v[1] + v[2] + v[3];
                float q = v[0] * v[0] + v[1] * v[1] + v[2] * v[2] + v[3] * v[3];
#pragma unroll
                for (int msk = 1; msk < 16; msk <<= 1) {
                    s += __shfl_xor(s, msk);
                    q += __shfl_xor(q, msk);
                }
                float mu = s * (1.0f / 64.0f);
                float var = q * (1.0f / 64.0f) - mu * mu;
                float inv = rsqrtf(var + 1e-6f);
                int b = batch_idx[row];
                const float* sbp = s_ss + b * 128;
#pragma unroll
                for (int n = 0; n < 4; ++n) {
                    float hn = (v[n] - mu) * inv;
                    float x = silu_f(hn * (1.0f + sbp[n * 16 + l15]) + sbp[64 + n * 16 + l15]);
                    int c = n * 16 + l15;
                    int pos = (((c >> 3) & 3) << 4) + ((c >> 5) << 3) + (c & 7);
                    dst_f8[row * 64 + pos] = (unsigned char)fp8_byte(x);
                }
            } else {
#pragma unroll
                for (int n = 0; n < 4; ++n)
                    dst_f32[row * 64 + n * 16 + l15] = v[n] + feats[row * 64 + n * 16 + l15];
            }
        }
    }
}

extern "C" void kernel_launch(void* const* d_in, const int* in_sizes, int n_in,
                              void* d_out, int out_size, void* d_ws, size_t ws_size,
                              hipStream_t stream) {
    (void)in_sizes; (void)n_in; (void)out_size; (void)ws_size;
    const float* feats = (const float*)d_in[0];
    const float* emb   = (const float*)d_in[1];
    const float* gamma = (const float*)d_in[2];
    const float* beta  = (const float*)d_in[3];
    const float* W1    = (const float*)d_in[4];
    const float* b1    = (const float*)d_in[5];
    const float* W2    = (const float*)d_in[6];
    const float* b2    = (const float*)d_in[7];
    const float* emb_W = (const float*)d_in[8];
    const float* emb_b = (const float*)d_in[9];
    const int* nbr     = (const int*)d_in[10];
    const int* bidx    = (const int*)d_in[11];
    float* out = (float*)d_out;

    const size_t HSZ = (size_t)(NV + ZROWS) * 64;  // fp8 buffer with zero region
    char* ws = (char*)d_ws;
    unsigned char* W1f  = (unsigned char*)(ws);                   // 110592 B
    unsigned char* W2f  = (unsigned char*)(ws + 110592);          // 110592 B
    float* ss           = (float*)(ws + 221184);                  // 2048 B
    unsigned char* h0   = (unsigned char*)(ws + 223232);
    unsigned char* h2   = (unsigned char*)(ws + 223232 + HSZ);
    short* nbr_s        = (short*)(ws + 223232 + 2 * HSZ);        // [27,NV] int16 deltas

    pre_kernel<<<8941, 256, 0, stream>>>(feats, emb, gamma, beta, W1, W2, emb_W, emb_b,
                                         nbr, W1f, W2f, ss, h0, h2, nbr_s);
    conv_kernel<0><<<1024, 256, 0, stream>>>(h0, W1f, nbr_s, bidx, ss, b1, nullptr, h2, nullptr);
    conv_kernel<1><<<1024, 256, 0, stream>>>(h2, W2f, nbr_s, bidx, ss, b2, feats, nullptr, out);
}

// Round 12
// 178.081 us; speedup vs baseline: 1.0223x; 1.0223x over previous
//
#include <hip/hip_runtime.h>
#include <hip/hip_bf16.h>
#include <math.h>

#define NV 131072
#define KOFF 27
#define ZROWS 64   // zero-pad region rows (spread hot line)
#define SENT (-32768)

typedef __attribute__((ext_vector_type(4))) float floatx4;
typedef __attribute__((ext_vector_type(4))) float float4v;
typedef __attribute__((ext_vector_type(2))) unsigned long ulong2v;
typedef __attribute__((ext_vector_type(2))) long long2v;
typedef __attribute__((ext_vector_type(4))) unsigned int uint4v;

__device__ inline float silu_f(float x) { return x / (1.0f + expf(-x)); }
__device__ inline unsigned int fp8_byte(float x) {
    return __builtin_amdgcn_cvt_pk_fp8_f32(x, x, 0, false) & 0xFF;
}

// h fp8 row layout (64 B): byte pos = quad*16 + half*8 + j  <->  channel half*32 + quad*8 + j.
// W rows use the SAME cin permutation, so one ds_read_b128 per cout-row gives both
// ks-halves of the B fragment, byte-aligned with the A fragment's MFMA k-index.

// ---------- fused pre kernel: role-partitioned grid ----------
// [0,512): nbr -> nbr_s [27][NV] int16 row-deltas (SENT = missing)
// [512,8704): LN1+silu -> h0 fp8 (16 lanes/row)
// [8704,8812): W1/W2 -> fp8 [k][cout][64B cin-permuted]
// [8812,8940): FiLM
// [8940]: zero-pad regions of h0/h2
__global__ void pre_kernel(const float* __restrict__ feats, const float* __restrict__ emb,
                           const float* __restrict__ gamma, const float* __restrict__ beta,
                           const float* __restrict__ W1, const float* __restrict__ W2,
                           const float* __restrict__ emb_W, const float* __restrict__ emb_b,
                           const int* __restrict__ nbr,
                           unsigned char* __restrict__ W1f, unsigned char* __restrict__ W2f,
                           float* __restrict__ ss, unsigned char* __restrict__ h0,
                           unsigned char* __restrict__ h2, short* __restrict__ nbr_s) {
    int gid = blockIdx.x, tid = threadIdx.x;
    if (gid < 512) {
        __shared__ int s[256 * KOFF];
        int r0 = gid * 256;
        for (int i = tid; i < 256 * KOFF; i += 256) s[i] = nbr[r0 * KOFF + i];
        __syncthreads();
        int r = r0 + tid;
#pragma unroll
        for (int k = 0; k < KOFF; ++k) {
            int v = s[tid * KOFF + k];
            nbr_s[k * NV + r] = (short)((v == NV) ? SENT : (v - r));  // |delta| <= 4161
        }
    } else if (gid < 8704) {
        int row = (gid - 512) * 16 + (tid >> 4);
        int t = tid & 15;
        float4v x = ((const float4v*)feats)[row * 16 + t];
        float s = x.x + x.y + x.z + x.w;
#pragma unroll
        for (int m = 1; m < 16; m <<= 1) s += __shfl_xor(s, m);
        float mu = s * (1.0f / 64.0f);
        float d0 = x.x - mu, d1 = x.y - mu, d2 = x.z - mu, d3 = x.w - mu;
        float q = d0 * d0 + d1 * d1 + d2 * d2 + d3 * d3;
#pragma unroll
        for (int m = 1; m < 16; m <<= 1) q += __shfl_xor(q, m);
        float inv = rsqrtf(q * (1.0f / 64.0f) + 1e-6f);
        float4v g = ((const float4v*)gamma)[t], b = ((const float4v*)beta)[t];
        float v0 = silu_f(d0 * inv * g.x + b.x);
        float v1 = silu_f(d1 * inv * g.y + b.y);
        float v2 = silu_f(d2 * inv * g.z + b.z);
        float v3 = silu_f(d3 * inv * g.w + b.w);
        unsigned int pk = __builtin_amdgcn_cvt_pk_fp8_f32(v0, v1, 0, false);
        pk = __builtin_amdgcn_cvt_pk_fp8_f32(v2, v3, pk, true);
        int pos = ((t >> 1) & 3) * 16 + (t >> 3) * 8 + (t & 1) * 4;
        *(unsigned int*)(h0 + row * 64 + pos) = pk;
    } else if (gid < 8812) {
        int t = (gid - 8704) * 256 + tid;  // dword idx < 27648
        if (t < 27648) {
            int k = t >> 10, rem = t & 1023, cout = rem >> 4, d = rem & 15;
            // output dword d of the permuted row covers cin0..cin0+3
            int cin0 = ((d >> 1) & 1) * 32 + (d >> 2) * 8 + (d & 1) * 4;
            const float* wsrc1 = W1 + k * 4096 + cin0 * 64 + cout;
            const float* wsrc2 = W2 + k * 4096 + cin0 * 64 + cout;
            unsigned int p1 = __builtin_amdgcn_cvt_pk_fp8_f32(wsrc1[0], wsrc1[64], 0, false);
            p1 = __builtin_amdgcn_cvt_pk_fp8_f32(wsrc1[128], wsrc1[192], p1, true);
            unsigned int p2 = __builtin_amdgcn_cvt_pk_fp8_f32(wsrc2[0], wsrc2[64], 0, false);
            p2 = __builtin_amdgcn_cvt_pk_fp8_f32(wsrc2[128], wsrc2[192], p2, true);
            ((unsigned int*)W1f)[t] = p1;
            ((unsigned int*)W2f)[t] = p2;
        }
    } else if (gid < 8940) {
        int wv = (gid - 8812) * 4 + (tid >> 6);  // 0..511
        int lane = tid & 63;
        int b = wv >> 7, c = wv & 127;
        float acc = 0.0f;
#pragma unroll
        for (int i = 0; i < 8; ++i) {
            int e = i * 64 + lane;
            acc += silu_f(emb[b * 512 + e]) * emb_W[e * 128 + c];
        }
#pragma unroll
        for (int m = 1; m < 64; m <<= 1) acc += __shfl_xor(acc, m);
        if (lane == 0) ss[wv] = acc + emb_b[c];
    } else {
        if (tid < 256) {
            uint4v z = (uint4v){0, 0, 0, 0};
            ((uint4v*)(h0 + NV * 64))[tid] = z;
            ((uint4v*)(h2 + NV * 64))[tid] = z;
        }
    }
}

// ---------- gather-MFMA sparse conv, fp8; ALL 27 W tiles LDS-resident; barrier-free ----
// 512 threads = 8 waves x 64 rows = 512 rows/block; 256 blocks = 1 block/CU.
// Stall-free steady state: A prefetch distance 2 (unroll-2 renaming), idx distance 4,
// bf (LDS) prefetch distance 1 (W LDS is read-only after the single staging pass).
template <int EPI>
__global__ __launch_bounds__(512) void conv_kernel(
    const unsigned char* __restrict__ hsrc,    // [NV+ZROWS, 64B] fp8 permuted rows
    const unsigned char* __restrict__ Wf,      // [27][64][64B] fp8, cin-permuted
    const short* __restrict__ nbr_s,           // [27, NV] int16 deltas
    const int* __restrict__ batch_idx,         // [NV]
    const float* __restrict__ ss,              // [4, 128]
    const float* __restrict__ bias,            // [64]
    const float* __restrict__ feats,           // [NV, 64] (EPI=1)
    unsigned char* __restrict__ dst_f8, float* __restrict__ dst_f32) {
    __shared__ char sW[KOFF * 4608];  // 27 tiles, 64 rows x 72 B (pad vs conflicts) = 124 KB
    __shared__ float s_ss[512];

    int tid = threadIdx.x, lane = tid & 63, wave = tid >> 6;
    int l15 = lane & 15, quad = lane >> 4;
    int lb = (blockIdx.x & 7) * 32 + (blockIdx.x >> 3);  // XCD-contiguous logical block
    int roww = lb * 512 + wave * 64;

    const char* hb = (const char*)hsrc;
    const ulong2v* w16 = (const ulong2v*)Wf;  // 16B chunks: k*256 + cout*4 + q
    const short* nps = nbr_s + roww + l15;
    unsigned int bo[4];
#pragma unroll
    for (int m = 0; m < 4; ++m) bo[m] = (unsigned int)((roww + m * 16 + l15) << 6) + quad * 16;
    unsigned int zoq = (unsigned int)((NV + (lb & (ZROWS - 1))) << 6) + quad * 16;

    // ---- prologue global loads first (latency overlaps W staging) ----
    short ta[4], tb[4];
#pragma unroll
    for (int m = 0; m < 4; ++m) ta[m] = nps[m * 16];             // idx(0)
#pragma unroll
    for (int m = 0; m < 4; ++m) tb[m] = nps[NV + m * 16];        // idx(1)
    ulong2v aA[4], aB[4];
#pragma unroll
    for (int m = 0; m < 4; ++m) {
        int dd = (int)ta[m];
        aA[m] = *(const ulong2v*)(hb + ((dd == SENT) ? zoq : (bo[m] + (unsigned int)(dd << 6))));
    }
#pragma unroll
    for (int m = 0; m < 4; ++m) {
        int dd = (int)tb[m];
        aB[m] = *(const ulong2v*)(hb + ((dd == SENT) ? zoq : (bo[m] + (unsigned int)(dd << 6))));
    }
    short dA[4], dB[4];
#pragma unroll
    for (int m = 0; m < 4; ++m) dA[m] = nps[2 * (size_t)NV + m * 16];  // idx(2)
#pragma unroll
    for (int m = 0; m < 4; ++m) dB[m] = nps[3 * (size_t)NV + m * 16];  // idx(3)

    // ---- stage all 27 W tiles into LDS (once) ----
    for (int i = tid; i < KOFF * 256; i += 512) {
        int k = i >> 8, r = i & 255, co = r >> 2, q = r & 3;
        *(ulong2v*)(sW + k * 4608 + co * 72 + q * 16) = w16[i];
    }
    if (EPI == 0) s_ss[tid] = ss[tid];

    floatx4 acc[4][4];
#pragma unroll
    for (int m = 0; m < 4; ++m)
#pragma unroll
        for (int n = 0; n < 4; ++n) acc[m][n] = (floatx4){0.f, 0.f, 0.f, 0.f};

    __syncthreads();

    // bf(0) prologue read
    long2v bfA[4], bfB[4];
#pragma unroll
    for (int n = 0; n < 4; ++n)
        bfA[n] = *(const long2v*)(sW + (n * 16 + l15) * 72 + quad * 16);

#define ONE(K, ACUR, DCUR, BFCUR, BFNXT)                                                       \
    {                                                                                          \
        int kn = ((K) + 1 <= 26) ? (K) + 1 : 26;                                               \
        _Pragma("unroll") for (int n = 0; n < 4; ++n)                                          \
            BFNXT[n] = *(const long2v*)(sW + kn * 4608 + (n * 16 + l15) * 72 + quad * 16);     \
        _Pragma("unroll") for (int n = 0; n < 4; ++n) {                                        \
            _Pragma("unroll") for (int m = 0; m < 4; ++m)                                      \
                acc[m][n] = __builtin_amdgcn_mfma_f32_16x16x32_fp8_fp8((long)ACUR[m].x,        \
                                                                       BFCUR[n].x, acc[m][n], 0, 0, 0); \
        }                                                                                      \
        _Pragma("unroll") for (int n = 0; n < 4; ++n) {                                        \
            _Pragma("unroll") for (int m = 0; m < 4; ++m)                                      \
                acc[m][n] = __builtin_amdgcn_mfma_f32_16x16x32_fp8_fp8((long)ACUR[m].y,        \
                                                                       BFCUR[n].y, acc[m][n], 0, 0, 0); \
        }                                                                                      \
        int k4 = ((K) + 4 <= 26) ? (K) + 4 : 26;                                               \
        _Pragma("unroll") for (int m = 0; m < 4; ++m) {                                        \
            int dd = (int)DCUR[m];                                                             \
            unsigned int o = (dd == SENT) ? zoq : (bo[m] + (unsigned int)(dd << 6));           \
            ACUR[m] = *(const ulong2v*)(hb + o);                                               \
            DCUR[m] = nps[(size_t)k4 * NV + m * 16];                                           \
        }                                                                                      \
    }

#pragma unroll 1
    for (int p = 0; p < 13; ++p) {
        ONE(2 * p, aA, dA, bfA, bfB);
        ONE(2 * p + 1, aB, dB, bfB, bfA);
    }
    ONE(26, aA, dA, bfA, bfB);
#undef ONE

    // epilogue: C/D layout col = lane&15, row = quad*4 + r
    float bias_v[4];
#pragma unroll
    for (int n = 0; n < 4; ++n) bias_v[n] = bias[n * 16 + l15];

#pragma unroll
    for (int m = 0; m < 4; ++m) {
#pragma unroll
        for (int r = 0; r < 4; ++r) {
            int row = roww + m * 16 + quad * 4 + r;
            float v[4];
#pragma unroll
            for (int n = 0; n < 4; ++n) v[n] = acc[m][n][r] + bias_v[n];
            if (EPI == 0) {
                float s = v[0] + v[1] + v[2] + v[3];
                float q = v[0] * v[0] + v[1] * v[1] + v[2] * v[2] + v[3] * v[3];
#pragma unroll
                for (int msk = 1; msk < 16; msk <<= 1) {
                    s += __shfl_xor(s, msk);
                    q += __shfl_xor(q, msk);
                }
                float mu = s * (1.0f / 64.0f);
                float var = q * (1.0f / 64.0f) - mu * mu;
                float inv = rsqrtf(var + 1e-6f);
                int b = batch_idx[row];
                const float* sbp = s_ss + b * 128;
#pragma unroll
                for (int n = 0; n < 4; ++n) {
                    float hn = (v[n] - mu) * inv;
                    float x = silu_f(hn * (1.0f + sbp[n * 16 + l15]) + sbp[64 + n * 16 + l15]);
                    int c = n * 16 + l15;
                    int pos = (((c >> 3) & 3) << 4) + ((c >> 5) << 3) + (c & 7);
                    dst_f8[row * 64 + pos] = (unsigned char)fp8_byte(x);
                }
            } else {
#pragma unroll
                for (int n = 0; n < 4; ++n)
                    dst_f32[row * 64 + n * 16 + l15] = v[n] + feats[row * 64 + n * 16 + l15];
            }
        }
    }
}

extern "C" void kernel_launch(void* const* d_in, const int* in_sizes, int n_in,
                              void* d_out, int out_size, void* d_ws, size_t ws_size,
                              hipStream_t stream) {
    (void)in_sizes; (void)n_in; (void)out_size; (void)ws_size;
    const float* feats = (const float*)d_in[0];
    const float* emb   = (const float*)d_in[1];
    const float* gamma = (const float*)d_in[2];
    const float* beta  = (const float*)d_in[3];
    const float* W1    = (const float*)d_in[4];
    const float* b1    = (const float*)d_in[5];
    const float* W2    = (const float*)d_in[6];
    const float* b2    = (const float*)d_in[7];
    const float* emb_W = (const float*)d_in[8];
    const float* emb_b = (const float*)d_in[9];
    const int* nbr     = (const int*)d_in[10];
    const int* bidx    = (const int*)d_in[11];
    float* out = (float*)d_out;

    const size_t HSZ = (size_t)(NV + ZROWS) * 64;  // fp8 buffer with zero region
    char* ws = (char*)d_ws;
    unsigned char* W1f  = (unsigned char*)(ws);                   // 110592 B
    unsigned char* W2f  = (unsigned char*)(ws + 110592);          // 110592 B
    float* ss           = (float*)(ws + 221184);                  // 2048 B
    unsigned char* h0   = (unsigned char*)(ws + 223232);
    unsigned char* h2   = (unsigned char*)(ws + 223232 + HSZ);
    short* nbr_s        = (short*)(ws + 223232 + 2 * HSZ);        // [27,NV] int16 deltas

    pre_kernel<<<8941, 256, 0, stream>>>(feats, emb, gamma, beta, W1, W2, emb_W, emb_b,
                                         nbr, W1f, W2f, ss, h0, h2, nbr_s);
    conv_kernel<0><<<256, 512, 0, stream>>>(h0, W1f, nbr_s, bidx, ss, b1, nullptr, h2, nullptr);
    conv_kernel<1><<<256, 512, 0, stream>>>(h2, W2f, nbr_s, bidx, ss, b2, feats, nullptr, out);
}

// Round 13
// 174.155 us; speedup vs baseline: 1.0454x; 1.0225x over previous
//
#include <hip/hip_runtime.h>
#include <hip/hip_bf16.h>
#include <math.h>

#define NV 131072
#define KOFF 27
#define ZROWS 64   // zero-pad region rows (spread hot line)
#define SENT (-32768)
#define WSTRIDE 80            // LDS W row stride: 16B-aligned, 2-way bank spread
#define WTILE (64 * WSTRIDE)  // 5120 B per k-offset tile

typedef __attribute__((ext_vector_type(4))) float floatx4;
typedef __attribute__((ext_vector_type(4))) float float4v;
typedef __attribute__((ext_vector_type(4))) unsigned int uint4v;
typedef __attribute__((ext_vector_type(8))) int int8v;

__device__ inline float silu_f(float x) { return x / (1.0f + expf(-x)); }
__device__ inline unsigned int fp8_byte(float x) {
    return __builtin_amdgcn_cvt_pk_fp8_f32(x, x, 0, false) & 0xFF;
}
// load 32 contiguous bytes as an 8xi32 MFMA operand
__device__ inline int8v ld32(const char* p) {
    uint4v t0 = *(const uint4v*)(p);
    uint4v t1 = *(const uint4v*)(p + 16);
    return (int8v){(int)t0.x, (int)t0.y, (int)t0.z, (int)t0.w,
                   (int)t1.x, (int)t1.y, (int)t1.z, (int)t1.w};
}

// h rows: 64 B fp8, IDENTITY channel order. MFMA 16x16x128 operands: lane(l15,quad):
// quad 0/1 -> offset k0 bytes (quad&1)*32..+31 ; quad 2/3 -> offset k1, same bytes.
// A and B share this assignment exactly, so the pairing cancels (layout-proof).

// ---------- fused pre kernel: role-partitioned grid ----------
// [0,512): nbr -> nbr_s [28][NV] int16 row-deltas (SENT = missing; row 27 = all SENT)
// [512,8704): LN1+silu -> h0 fp8 identity rows
// [8704,8812): W1/W2 -> fp8 [k][cout][cin] identity
// [8812,8940): FiLM ; [8940]: zero-pad regions
__global__ void pre_kernel(const float* __restrict__ feats, const float* __restrict__ emb,
                           const float* __restrict__ gamma, const float* __restrict__ beta,
                           const float* __restrict__ W1, const float* __restrict__ W2,
                           const float* __restrict__ emb_W, const float* __restrict__ emb_b,
                           const int* __restrict__ nbr,
                           unsigned char* __restrict__ W1f, unsigned char* __restrict__ W2f,
                           float* __restrict__ ss, unsigned char* __restrict__ h0,
                           unsigned char* __restrict__ h2, short* __restrict__ nbr_s) {
    int gid = blockIdx.x, tid = threadIdx.x;
    if (gid < 512) {
        __shared__ int s[256 * KOFF];
        int r0 = gid * 256;
        for (int i = tid; i < 256 * KOFF; i += 256) s[i] = nbr[r0 * KOFF + i];
        __syncthreads();
        int r = r0 + tid;
#pragma unroll
        for (int k = 0; k < KOFF; ++k) {
            int v = s[tid * KOFF + k];
            nbr_s[k * NV + r] = (short)((v == NV) ? SENT : (v - r));
        }
        nbr_s[KOFF * NV + r] = (short)SENT;  // padded 28th offset
    } else if (gid < 8704) {
        int row = (gid - 512) * 16 + (tid >> 4);
        int t = tid & 15;
        float4v x = ((const float4v*)feats)[row * 16 + t];
        float s = x.x + x.y + x.z + x.w;
#pragma unroll
        for (int m = 1; m < 16; m <<= 1) s += __shfl_xor(s, m);
        float mu = s * (1.0f / 64.0f);
        float d0 = x.x - mu, d1 = x.y - mu, d2 = x.z - mu, d3 = x.w - mu;
        float q = d0 * d0 + d1 * d1 + d2 * d2 + d3 * d3;
#pragma unroll
        for (int m = 1; m < 16; m <<= 1) q += __shfl_xor(q, m);
        float inv = rsqrtf(q * (1.0f / 64.0f) + 1e-6f);
        float4v g = ((const float4v*)gamma)[t], b = ((const float4v*)beta)[t];
        float v0 = silu_f(d0 * inv * g.x + b.x);
        float v1 = silu_f(d1 * inv * g.y + b.y);
        float v2 = silu_f(d2 * inv * g.z + b.z);
        float v3 = silu_f(d3 * inv * g.w + b.w);
        unsigned int pk = __builtin_amdgcn_cvt_pk_fp8_f32(v0, v1, 0, false);
        pk = __builtin_amdgcn_cvt_pk_fp8_f32(v2, v3, pk, true);
        *(unsigned int*)(h0 + row * 64 + 4 * t) = pk;  // identity channels 4t..4t+3
    } else if (gid < 8812) {
        int t = (gid - 8704) * 256 + tid;  // dword idx < 27648
        if (t < 27648) {
            int k = t >> 10, cout = (t >> 4) & 63, d = t & 15;
            const float* wsrc1 = W1 + k * 4096 + (4 * d) * 64 + cout;
            const float* wsrc2 = W2 + k * 4096 + (4 * d) * 64 + cout;
            unsigned int p1 = __builtin_amdgcn_cvt_pk_fp8_f32(wsrc1[0], wsrc1[64], 0, false);
            p1 = __builtin_amdgcn_cvt_pk_fp8_f32(wsrc1[128], wsrc1[192], p1, true);
            unsigned int p2 = __builtin_amdgcn_cvt_pk_fp8_f32(wsrc2[0], wsrc2[64], 0, false);
            p2 = __builtin_amdgcn_cvt_pk_fp8_f32(wsrc2[128], wsrc2[192], p2, true);
            ((unsigned int*)W1f)[t] = p1;
            ((unsigned int*)W2f)[t] = p2;
        }
    } else if (gid < 8940) {
        int wv = (gid - 8812) * 4 + (tid >> 6);  // 0..511
        int lane = tid & 63;
        int b = wv >> 7, c = wv & 127;
        float acc = 0.0f;
#pragma unroll
        for (int i = 0; i < 8; ++i) {
            int e = i * 64 + lane;
            acc += silu_f(emb[b * 512 + e]) * emb_W[e * 128 + c];
        }
#pragma unroll
        for (int m = 1; m < 64; m <<= 1) acc += __shfl_xor(acc, m);
        if (lane == 0) ss[wv] = acc + emb_b[c];
    } else {
        if (tid < 256) {
            uint4v z = (uint4v){0, 0, 0, 0};
            ((uint4v*)(h0 + NV * 64))[tid] = z;
            ((uint4v*)(h2 + NV * 64))[tid] = z;
        }
    }
}

// ---------- gather-MFMA sparse conv, MX-fp8 K=128 (2 k-offsets per MFMA) ----------
// 512 thr = 8 waves x 64 rows; 256 blocks = 1 block/CU. All 28 W tiles LDS-resident;
// barrier-free K-loop (14 pairs), unroll-2 renaming: A dist-1 pair, idx dist-2, bf dist-1.
template <int EPI>
__global__ __launch_bounds__(512, 2) void conv_kernel(
    const unsigned char* __restrict__ hsrc,    // [NV+ZROWS, 64B] fp8 identity rows
    const unsigned char* __restrict__ Wf,      // [27][64][64B] fp8 identity cin
    const short* __restrict__ nbr_s,           // [28, NV] int16 deltas
    const int* __restrict__ batch_idx,         // [NV]
    const float* __restrict__ ss,              // [4, 128]
    const float* __restrict__ bias,            // [64]
    const float* __restrict__ feats,           // [NV, 64] (EPI=1)
    unsigned char* __restrict__ dst_f8, float* __restrict__ dst_f32) {
    __shared__ char sW[28 * WTILE];  // 140 KB
    __shared__ float s_ss[512];

    int tid = threadIdx.x, lane = tid & 63, wave = tid >> 6;
    int l15 = lane & 15, quad = lane >> 4, qh = quad >> 1, ql = quad & 1;
    int lb = (blockIdx.x & 7) * 32 + (blockIdx.x >> 3);  // XCD-contiguous logical block
    int roww = lb * 512 + wave * 64;

    const char* hb = (const char*)hsrc;
    const uint4v* w16 = (const uint4v*)Wf;  // 16B chunks: k*256 + cout*4 + q
    const short* npq = nbr_s + (size_t)qh * NV + roww + l15;  // this lane's offset half
    unsigned int bo[4];
#pragma unroll
    for (int m = 0; m < 4; ++m)
        bo[m] = (unsigned int)((roww + m * 16 + l15) << 6) + ql * 32;
    unsigned int zoq = (unsigned int)((NV + (lb & (ZROWS - 1))) << 6) + ql * 32;

    // ---- prologue: idx(0)->A(0); idx(1),(2) in regs ----
    short dA[4], dB[4];
#pragma unroll
    for (int m = 0; m < 4; ++m) dA[m] = npq[m * 16];                       // pair 0
#pragma unroll
    for (int m = 0; m < 4; ++m) dB[m] = npq[2 * (size_t)NV + m * 16];      // pair 1
    int8v aA[4], aB[4];
#pragma unroll
    for (int m = 0; m < 4; ++m) {
        int dd = (int)dA[m];
        unsigned int o = (dd == SENT) ? zoq : bo[m] + (unsigned int)(dd << 6);
        aA[m] = ld32(hb + o);
    }
#pragma unroll
    for (int m = 0; m < 4; ++m) dA[m] = npq[4 * (size_t)NV + m * 16];      // pair 2

    // ---- stage all W tiles (27 real + zero 28th) ----
    for (int i = tid; i < 28 * 256; i += 512) {
        int k = i >> 8, r = i & 255, co = r >> 2, q = r & 3;
        uint4v v = (k < KOFF) ? w16[i] : (uint4v){0, 0, 0, 0};
        *(uint4v*)(sW + k * WTILE + co * WSTRIDE + q * 16) = v;
    }
    if (EPI == 0) s_ss[tid] = ss[tid];

    floatx4 acc[4][4];
#pragma unroll
    for (int m = 0; m < 4; ++m)
#pragma unroll
        for (int n = 0; n < 4; ++n) acc[m][n] = (floatx4){0.f, 0.f, 0.f, 0.f};

    __syncthreads();

    // bf(0)
    int8v bfA[4], bfB[4];
    {
        const char* kb = sW + qh * WTILE + ql * 32;
#pragma unroll
        for (int n = 0; n < 4; ++n) bfA[n] = ld32(kb + (n * 16 + l15) * WSTRIDE);
    }

#define PAIR(P, ACUR, BFCUR, ANXT, DNXT, BFNXT)                                              \
    {                                                                                        \
        int pb = ((P) + 1 <= 13) ? (P) + 1 : 13;                                             \
        const char* kb = sW + (2 * pb + qh) * WTILE + ql * 32;                               \
        _Pragma("unroll") for (int n = 0; n < 4; ++n)                                        \
            BFNXT[n] = ld32(kb + (n * 16 + l15) * WSTRIDE);                                  \
        _Pragma("unroll") for (int m = 0; m < 4; ++m) {                                      \
            int dd = (int)DNXT[m];                                                           \
            unsigned int o = (dd == SENT) ? zoq : bo[m] + (unsigned int)(dd << 6);           \
            ANXT[m] = ld32(hb + o);                                                          \
        }                                                                                    \
        int pn = ((P) + 3 <= 13) ? (P) + 3 : 13;                                             \
        _Pragma("unroll") for (int m = 0; m < 4; ++m)                                        \
            DNXT[m] = npq[(size_t)(2 * pn) * NV + m * 16];                                   \
        _Pragma("unroll") for (int m = 0; m < 4; ++m) {                                      \
            _Pragma("unroll") for (int n = 0; n < 4; ++n)                                    \
                acc[m][n] = __builtin_amdgcn_mfma_scale_f32_16x16x128_f8f6f4(                \
                    ACUR[m], BFCUR[n], acc[m][n], 0, 0, 0, 127, 0, 127);                     \
        }                                                                                    \
    }

#pragma unroll 1
    for (int p = 0; p < 14; p += 2) {
        PAIR(p, aA, bfA, aB, dB, bfB);
        PAIR(p + 1, aB, bfB, aA, dA, bfA);
    }
#undef PAIR

    // epilogue: C/D layout col = lane&15, row = quad*4 + r
    float bias_v[4];
#pragma unroll
    for (int n = 0; n < 4; ++n) bias_v[n] = bias[n * 16 + l15];

#pragma unroll
    for (int m = 0; m < 4; ++m) {
#pragma unroll
        for (int r = 0; r < 4; ++r) {
            int row = roww + m * 16 + quad * 4 + r;
            float v[4];
#pragma unroll
            for (int n = 0; n < 4; ++n) v[n] = acc[m][n][r] + bias_v[n];
            if (EPI == 0) {
                float s = v[0] + v[1] + v[2] + v[3];
                float q = v[0] * v[0] + v[1] * v[1] + v[2] * v[2] + v[3] * v[3];
#pragma unroll
                for (int msk = 1; msk < 16; msk <<= 1) {
                    s += __shfl_xor(s, msk);
                    q += __shfl_xor(q, msk);
                }
                float mu = s * (1.0f / 64.0f);
                float var = q * (1.0f / 64.0f) - mu * mu;
                float inv = rsqrtf(var + 1e-6f);
                int b = batch_idx[row];
                const float* sbp = s_ss + b * 128;
#pragma unroll
                for (int n = 0; n < 4; ++n) {
                    float hn = (v[n] - mu) * inv;
                    float x = silu_f(hn * (1.0f + sbp[n * 16 + l15]) + sbp[64 + n * 16 + l15]);
                    dst_f8[row * 64 + n * 16 + l15] = (unsigned char)fp8_byte(x);
                }
            } else {
#pragma unroll
                for (int n = 0; n < 4; ++n)
                    dst_f32[row * 64 + n * 16 + l15] = v[n] + feats[row * 64 + n * 16 + l15];
            }
        }
    }
}

extern "C" void kernel_launch(void* const* d_in, const int* in_sizes, int n_in,
                              void* d_out, int out_size, void* d_ws, size_t ws_size,
                              hipStream_t stream) {
    (void)in_sizes; (void)n_in; (void)out_size; (void)ws_size;
    const float* feats = (const float*)d_in[0];
    const float* emb   = (const float*)d_in[1];
    const float* gamma = (const float*)d_in[2];
    const float* beta  = (const float*)d_in[3];
    const float* W1    = (const float*)d_in[4];
    const float* b1    = (const float*)d_in[5];
    const float* W2    = (const float*)d_in[6];
    const float* b2    = (const float*)d_in[7];
    const float* emb_W = (const float*)d_in[8];
    const float* emb_b = (const float*)d_in[9];
    const int* nbr     = (const int*)d_in[10];
    const int* bidx    = (const int*)d_in[11];
    float* out = (float*)d_out;

    const size_t HSZ = (size_t)(NV + ZROWS) * 64;  // fp8 buffer with zero region
    char* ws = (char*)d_ws;
    unsigned char* W1f  = (unsigned char*)(ws);                   // 110592 B
    unsigned char* W2f  = (unsigned char*)(ws + 110592);          // 110592 B
    float* ss           = (float*)(ws + 221184);                  // 2048 B
    unsigned char* h0   = (unsigned char*)(ws + 223232);
    unsigned char* h2   = (unsigned char*)(ws + 223232 + HSZ);
    short* nbr_s        = (short*)(ws + 223232 + 2 * HSZ);        // [28,NV] int16 deltas

    pre_kernel<<<8941, 256, 0, stream>>>(feats, emb, gamma, beta, W1, W2, emb_W, emb_b,
                                         nbr, W1f, W2f, ss, h0, h2, nbr_s);
    conv_kernel<0><<<256, 512, 0, stream>>>(h0, W1f, nbr_s, bidx, ss, b1, nullptr, h2, nullptr);
    conv_kernel<1><<<256, 512, 0, stream>>>(h2, W2f, nbr_s, bidx, ss, b2, feats, nullptr, out);
}